// Round 3
// baseline (165.345 us; speedup 1.0000x reference)
//
#include <hip/hip_runtime.h>
#include <stdint.h>

typedef uint32_t u32;
typedef unsigned long long u64;

#define NB 8
#define NPER 4000
#define NC 91
#define NCLS 90
#define NDET 100
#define CHUNKS 64
#define RPB 63         // rows per k_score block; 64*63=4032 covers 4000 w/ guard
#define LBIN 16        // LDS staging per class per chunk (avg ~1.6 used)
#define CCAP 63        // per-(chunk,class) global bin cap == rows/chunk (EXACT)
#define BINCAP 512     // per-(image,class) NMS pool clamp (avg ~103)
#define SURVCAP 9216   // fixed survivor slots: 90 classes x 100 + pad
#define NSFIX (NCLS * NDET)  // 9000 real slots
#define FKCAP 1024     // k_top compacted pool (100 + bin-B ties)
#define VPT 36         // k_top values/thread = SURVCAP/256
#define NBIN 1152      // histogram bins over score bits; 1127 used (18/lane)
#define SLO 0x3D4CCCCEu  // bits(0.05); all survivor scores strictly above
#define SSH 15         // bin = (bits - SLO) >> SSH; max idx 0x2333333>>15 = 1126

// ---------------------------------------------------------------- decode ----
// bit-identical to reference op order (verified absmax 0.0 in R1-R15)
__device__ __forceinline__ float4 decode_clip(float4 rel, float w, float h,
                                              float cx, float cy, float W, float H) {
  const float XCLIP = 4.135166556742356f;  // log(1000/16)
  float dx = rel.x / 10.0f;
  float dy = rel.y / 10.0f;
  float dw = fminf(rel.z / 5.0f, XCLIP);
  float dh = fminf(rel.w / 5.0f, XCLIP);
  float qcx = dx * w + cx;
  float qcy = dy * h + cy;
  float qw = expf(dw) * w;
  float qh = expf(dh) * h;
  float x1 = qcx - 0.5f * qw, y1 = qcy - 0.5f * qh;
  float x2 = qcx + 0.5f * qw, y2 = qcy + 0.5f * qh;
  x1 = fminf(fmaxf(x1, 0.0f), W);
  x2 = fminf(fmaxf(x2, 0.0f), W);
  y1 = fminf(fmaxf(y1, 0.0f), H);
  y2 = fminf(fmaxf(y2, 0.0f), H);
  return make_float4(x1, y1, x2, y2);
}

__device__ __forceinline__ float rdlane(float v, int sl) {
  return __int_as_float(__builtin_amdgcn_readlane(__float_as_int(v), sl));
}

// ---------------------------------------------------------------- k_score ---
__device__ __forceinline__ void emit_row(int r, int rl, int lane, float sA, float sB,
    float W, float H, const float4* __restrict__ props4, const float4* __restrict__ breg4,
    u32* s_cnt, u64 (*s_key)[LBIN], float4 (*s_box)[LBIN],
    size_t chbase, u64* __restrict__ bins_key, float4* __restrict__ bins_box) {
  bool eA_ok = (lane >= 1) && (sA > 0.05f);
  bool eB_ok = (lane < NC - 64) && (sB > 0.05f);
  if (!(eA_ok || eB_ok)) return;
  float4 p = props4[r];
  float w = p.z - p.x, h = p.w - p.y;
  float cx = p.x + 0.5f * w, cy = p.y + 0.5f * h;
  if (eA_ok) {
    float4 raw = decode_clip(breg4[(size_t)r * NC + lane], w, h, cx, cy, W, H);
    if (((raw.z - raw.x) >= 0.01f) && ((raw.w - raw.y) >= 0.01f)) {
      int ci = lane - 1;
      u32 orig = (u32)(rl * NCLS + ci);
      u64 key = ((u64)__float_as_uint(sA) << 22) | (u64)(0x3FFFFFu - orig);
      u32 lp = atomicAdd(&s_cnt[ci], 1u);  // LDS only
      if (lp < LBIN) { s_key[ci][lp] = key; s_box[ci][lp] = raw; }
      else if (lp < CCAP) {  // block-private global slot, no atomic
        size_t o = (chbase + ci) * CCAP + lp;
        bins_key[o] = key; bins_box[o] = raw;
      }
    }
  }
  if (eB_ok) {
    float4 raw = decode_clip(breg4[(size_t)r * NC + 64 + lane], w, h, cx, cy, W, H);
    if (((raw.z - raw.x) >= 0.01f) && ((raw.w - raw.y) >= 0.01f)) {
      int ci = 63 + lane;
      u32 orig = (u32)(rl * NCLS + ci);
      u64 key = ((u64)__float_as_uint(sB) << 22) | (u64)(0x3FFFFFu - orig);
      u32 lp = atomicAdd(&s_cnt[ci], 1u);
      if (lp < LBIN) { s_key[ci][lp] = key; s_box[ci][lp] = raw; }
      else if (lp < CCAP) {
        size_t o = (chbase + ci) * CCAP + lp;
        bins_key[o] = key; bins_box[o] = raw;
      }
    }
  }
}

// Front-end: softmax + decode + filter. R16: 512-thread blocks (8 waves, 4
// row-pair iterations) instead of 1024 -- occupancy becomes 8-wave-granular
// (VGPR<=84 still gives 24 waves/CU vs 16 at the old 1024-thread quantum).
// Per-row math, emit predicate, and shfl reduction order are UNCHANGED
// (bit-identical); only the wave->row mapping changes, which is output-
// invariant (unique keys, per-(chunk,class) emits never exceed CCAP, and
// k_nms_class sorts canonically).
__global__ __launch_bounds__(512) void k_score(const float* __restrict__ logits,
    const float* __restrict__ boxreg, const float* __restrict__ props,
    const int* __restrict__ dh, const int* __restrict__ dw,
    u32* cnt_g, u64* bins_key, float4* bins_box) {
  __shared__ u64 s_key[NCLS][LBIN];
  __shared__ float4 s_box[NCLS][LBIN];
  __shared__ u32 s_cnt[NCLS];
  int tid = threadIdx.x;
  int b = blockIdx.x / CHUNKS;
  int chunk = blockIdx.x % CHUNKS;
  int wave = tid >> 6, lane = tid & 63;  // wave in 0..7
  if (tid < NCLS) s_cnt[tid] = 0u;
  __syncthreads();

  float H = (float)dh[0], W = (float)dw[0];
  const float4* props4 = (const float4*)props;
  const float4* breg4 = (const float4*)boxreg;
  size_t chbase = ((size_t)(b * CHUNKS + chunk)) * NCLS;  // *CCAP for bins

  for (int it = 0; it < 4; ++it) {
    int rloc = wave + (it << 3);   // 0..31
    int rloc1 = rloc + 32;         // 32..63 (63 guarded off)
    int rl0 = chunk * RPB + rloc;
    int rl1 = chunk * RPB + rloc1;
    bool v0 = (rl0 < NPER);
    bool v1 = (rloc1 < RPB) && (rl1 < NPER);
    int r0 = b * NPER + (v0 ? rl0 : 0);
    int r1 = b * NPER + (v1 ? rl1 : 0);
    const float* l0 = logits + (size_t)r0 * NC;
    const float* l1 = logits + (size_t)r1 * NC;
    float xA0 = l0[lane];
    float xA1 = l1[lane];
    float xB0 = (lane < NC - 64) ? l0[64 + lane] : -3.0e38f;
    float xB1 = (lane < NC - 64) ? l1[64 + lane] : -3.0e38f;
    float mx0 = fmaxf(xA0, xB0);
    float mx1 = fmaxf(xA1, xB1);
    for (int o = 32; o; o >>= 1) {
      mx0 = fmaxf(mx0, __shfl_xor(mx0, o));
      mx1 = fmaxf(mx1, __shfl_xor(mx1, o));
    }
    float eA0 = expf(xA0 - mx0);
    float eA1 = expf(xA1 - mx1);
    float eB0 = (lane < NC - 64) ? expf(xB0 - mx0) : 0.0f;
    float eB1 = (lane < NC - 64) ? expf(xB1 - mx1) : 0.0f;
    float sm0 = eA0 + eB0;
    float sm1 = eA1 + eB1;
    for (int o = 32; o; o >>= 1) {
      sm0 += __shfl_xor(sm0, o);
      sm1 += __shfl_xor(sm1, o);
    }
    if (v0) emit_row(r0, rl0, lane, eA0 / sm0, eB0 / sm0, W, H, props4, breg4,
                     s_cnt, s_key, s_box, chbase, bins_key, bins_box);
    if (v1) emit_row(r1, rl1, lane, eA1 / sm1, eB1 / sm1, W, H, props4, breg4,
                     s_cnt, s_key, s_box, chbase, bins_key, bins_box);
  }
  __syncthreads();
  if (tid < NCLS) cnt_g[chbase + tid] = s_cnt[tid];  // plain store
  for (int idx = tid; idx < NCLS * LBIN; idx += 512) {  // cooperative LDS flush
    int ci = idx / LBIN, j = idx % LBIN;
    if ((u32)j < s_cnt[ci]) {
      size_t o = (chbase + ci) * CCAP + (u32)j;
      bins_key[o] = s_key[ci][j];
      bins_box[o] = s_box[ci][j];
    }
  }
}

// Per-(image,class) greedy NMS. R16: DUAL-SELECT greedy -- per ballot round
// take the two lowest alive bits j0 < j1. j1 is the sequential algorithm's
// next pick iff IoU(A0,A1) <= 0.5 (no bits lie between j0 and j1, and j1
// survives A0 exactly when that test passes), so selecting both per round
// halves the serial {ctz -> readlane -> iou -> ballot} chain count while
// keeping selection order, survivor slots, and suppression sets provably
// identical to the one-at-a-time loop -> bit-identical output.
__global__ __launch_bounds__(256) void k_nms_class(const u32* __restrict__ cnt_g,
    const u64* __restrict__ bins_key, const float4* __restrict__ bins_box,
    u64* skey, float4* sbox, const int* __restrict__ dh, const int* __restrict__ dw) {
  __shared__ u64 k[BINCAP];       // unsorted keys
  __shared__ float4 boxu[BINCAP]; // unsorted boxes
  __shared__ u64 ks[BINCAP];      // rank-sorted keys (desc)
  __shared__ float4 boxs[BINCAP]; // rank-sorted boxes
  __shared__ float4 s_sb[NDET];   // survivor offset boxes (IoU space)
  __shared__ float s_sa[NDET];
  __shared__ u64 s_sk[NDET];
  __shared__ u32 s_sid[NDET];
  __shared__ u32 s_off[64];
  __shared__ u32 s_c[64];
  __shared__ u32 s_n;

  int b = blockIdx.x / NCLS;
  int ci = blockIdx.x % NCLS;
  int tid = threadIdx.x;
  u64* outk = skey + (size_t)b * SURVCAP + (size_t)ci * NDET;
  float4* outb = sbox + (size_t)b * SURVCAP + (size_t)ci * NDET;

  if (tid < 64) {  // lane == chunk: counts + wave prefix scan
    u32 c = cnt_g[((size_t)(b * CHUNKS + tid)) * NCLS + ci];
    if (c > CCAP) c = CCAP;
    s_c[tid] = c;
    u32 inc = c;
    for (int o = 1; o < 64; o <<= 1) {
      u32 v = __shfl_up(inc, o);
      if (tid >= o) inc += v;
    }
    s_off[tid] = inc - c;
    if (tid == 63) s_n = (inc > BINCAP) ? BINCAP : inc;
  }
  __syncthreads();
  int n = (int)s_n;
  if (n <= 0) {
    for (int i = tid; i < NDET; i += 256) outk[i] = 0ull;
    return;
  }
  {  // cooperative gather: 4 threads per chunk
    int chunk = tid & 63, start = tid >> 6;
    u32 cc = s_c[chunk], of = s_off[chunk];
    size_t src = (((size_t)(b * CHUNKS + chunk)) * NCLS + ci) * CCAP;
    for (u32 i = (u32)start; i < cc; i += 4) {
      u32 d = of + i;
      if (d < (u32)BINCAP) { k[d] = bins_key[src + i]; boxu[d] = bins_box[src + i]; }
    }
  }
  __syncthreads();
  for (int i = tid; i < n; i += 256) {  // rank sort: broadcast reads, no barriers
    u64 ki = k[i];
    u32 rank = 0;
    int j = 0;
    for (; j + 4 <= n; j += 4) {
      rank += (k[j] > ki) ? 1u : 0u;
      rank += (k[j + 1] > ki) ? 1u : 0u;
      rank += (k[j + 2] > ki) ? 1u : 0u;
      rank += (k[j + 3] > ki) ? 1u : 0u;
    }
    for (; j < n; ++j) rank += (k[j] > ki) ? 1u : 0u;
    ks[rank] = ki;
    boxs[rank] = boxu[i];
  }
  __syncthreads();
  if (tid >= 64) return;  // wave 0 continues barrier-free

  float H = (float)dh[0], W = (float)dw[0];
  float loff = (fmaxf(H, W) + 1.0f) * (float)(ci + 1);
  int lane = tid;
  int S = 0;
  for (int base = 0; base < n && S < NDET; base += 64) {
    int i = base + lane;
    bool have = (i < n);
    u64 mykey = 0ull;
    float4 Bb = make_float4(0.f, 0.f, 0.f, 0.f);
    float aB = 0.f;
    if (have) {
      mykey = ks[i];
      float4 raw = boxs[i];
      Bb = make_float4(raw.x + loff, raw.y + loff, raw.z + loff, raw.w + loff);
      aB = (Bb.z - Bb.x) * (Bb.w - Bb.y);
    }
    bool alive = have;
    for (int s = 0; s < S; ++s) {  // independent LDS reads, pipelined
      float4 A = s_sb[s];
      float aA = s_sa[s];
      float ix1 = fmaxf(A.x, Bb.x), iy1 = fmaxf(A.y, Bb.y);
      float ix2 = fminf(A.z, Bb.z), iy2 = fminf(A.w, Bb.w);
      float inter = fmaxf(ix2 - ix1, 0.0f) * fmaxf(iy2 - iy1, 0.0f);
      float iou = inter / fmaxf(aA + aB - inter, 1e-9f);
      if (alive && iou > 0.5f) alive = false;
    }
    u64 mask = __ballot(alive);
    while (mask && S < NDET) {
      int j0 = __builtin_amdgcn_readfirstlane(__builtin_ctzll(mask));
      float A0x = rdlane(Bb.x, j0), A0y = rdlane(Bb.y, j0);
      float A0z = rdlane(Bb.z, j0), A0w = rdlane(Bb.w, j0);
      float a0 = rdlane(aB, j0);
      u64 m2 = mask & (mask - 1);  // alive bits after j0
      bool have1 = (m2 != 0ull) && (S + 1 < NDET);
      int j1 = 0;
      float A1x = 0.f, A1y = 0.f, A1z = 0.f, A1w = 0.f, a1 = 0.f;
      if (have1) {
        j1 = __builtin_amdgcn_readfirstlane(__builtin_ctzll(m2));
        A1x = rdlane(Bb.x, j1); A1y = rdlane(Bb.y, j1);
        A1z = rdlane(Bb.z, j1); A1w = rdlane(Bb.w, j1);
        a1 = rdlane(aB, j1);
      }
      // per-lane suppression vs A0
      float ix1 = fmaxf(A0x, Bb.x), iy1 = fmaxf(A0y, Bb.y);
      float ix2 = fminf(A0z, Bb.z), iy2 = fminf(A0w, Bb.w);
      float inter = fmaxf(ix2 - ix1, 0.0f) * fmaxf(iy2 - iy1, 0.0f);
      float iou0 = inter / fmaxf(a0 + aB - inter, 1e-9f);
      // is j1 the sequential next pick? (uniform: computed from scalars)
      bool sel1 = false;
      if (have1) {
        float jx1 = fmaxf(A0x, A1x), jy1 = fmaxf(A0y, A1y);
        float jx2 = fminf(A0z, A1z), jy2 = fminf(A0w, A1w);
        float jint = fmaxf(jx2 - jx1, 0.0f) * fmaxf(jy2 - jy1, 0.0f);
        float iou01 = jint / fmaxf(a0 + a1 - jint, 1e-9f);
        sel1 = !(iou01 > 0.5f);
      }
      if (lane == j0) {
        s_sb[S] = Bb; s_sa[S] = aB; s_sk[S] = mykey; s_sid[S] = (u32)i;
      }
      if (alive && iou0 > 0.5f) alive = false;  // j0 leaves (self-IoU=1);
                                                // unselected j1 leaves here too
      if (sel1) {
        if (lane == j1) {
          s_sb[S + 1] = Bb; s_sa[S + 1] = aB; s_sk[S + 1] = mykey; s_sid[S + 1] = (u32)i;
        }
        float kx1 = fmaxf(A1x, Bb.x), ky1 = fmaxf(A1y, Bb.y);
        float kx2 = fminf(A1z, Bb.z), ky2 = fminf(A1w, Bb.w);
        float kint = fmaxf(kx2 - kx1, 0.0f) * fmaxf(ky2 - ky1, 0.0f);
        float iou1 = kint / fmaxf(a1 + aB - kint, 1e-9f);
        if (alive && iou1 > 0.5f) alive = false;  // selected j1 leaves (self-IoU=1)
        S += 2;
      } else {
        S += 1;
      }
      mask = __ballot(alive);
    }
  }
  for (int i2 = lane; i2 < NDET; i2 += 64) {  // fixed slots, zero-padded
    if (i2 < S) {
      outk[i2] = s_sk[i2];
      outb[i2] = boxs[s_sid[i2]];
    } else {
      outk[i2] = 0ull;
    }
  }
}

// Per-image exact top-NDET over the fixed 9000 survivor slots (key==0 =
// empty, never selectable). R15 structure: ONE LDS histogram pass over the
// score bits + in-wave suffix scan locates threshold bin B (bin index is
// monotone in the score field; cum(B) >= NDET contains the exact top-100;
// count(bins > B) < NDET by maximality). Two-pass compact (bins>B then
// bin==B ties, FKCAP clamp) + rank sort -> bit-identical outputs.
__global__ __launch_bounds__(256) void k_top(const u64* __restrict__ skey,
    const float4* __restrict__ sbox, float* out) {
  __shared__ u32 hist[NBIN];
  __shared__ u64 fk[FKCAP];
  __shared__ u32 fs[FKCAP];
  __shared__ u64 okey[NDET];
  __shared__ u32 osrc[NDET];
  __shared__ u32 s_cnt[2];
  __shared__ u32 s_bin;

  int b = blockIdx.x;
  int tid = threadIdx.x;
  const u64* kb = skey + (size_t)b * SURVCAP;

  u32 sc[VPT];
#pragma unroll
  for (int v = 0; v < VPT; ++v) {
    u32 j = (u32)tid + (u32)v * 256u;
    sc[v] = (j < NSFIX) ? (u32)(kb[j] >> 22) : 0u;  // key==0 slots -> score 0
  }
  for (int i = tid; i < NBIN; i += 256) hist[i] = 0u;
  if (tid == 0) { s_cnt[0] = 0; s_cnt[1] = 0; }
  __syncthreads();

#pragma unroll
  for (int v = 0; v < VPT; ++v) {
    u32 s = sc[v];
    if (s > SLO) atomicAdd(&hist[(s - SLO) >> SSH], 1u);
  }
  __syncthreads();

  // wave 0: largest bin B with cum(B) = count(bins >= B) >= NDET; B=0 if none
  if (tid < 64) {
    int lane = tid;
    int base = lane * (NBIN / 64);  // 18 contiguous bins per lane
    u32 csum = 0;
#pragma unroll
    for (int kk2 = 0; kk2 < NBIN / 64; ++kk2) csum += hist[base + kk2];
    u32 suf = csum;                 // inclusive suffix scan across lanes
    for (int o = 1; o < 64; o <<= 1) {
      u32 v = __shfl_down(suf, o);
      if (lane + o < 64) suf += v;
    }
    u64 m = __ballot(suf >= NDET);  // prefix mask (suf non-increasing in lane)
    int B = 0;
    if (m) {
      int c = 63 - __builtin_clzll(m);              // largest chunk with suf>=NDET
      u32 rest = (c < 63) ? (u32)__shfl((int)suf, c + 1) : 0u;  // uniform
      u32 acc = rest;
      int cb = c * (NBIN / 64);
      for (int kk2 = (NBIN / 64) - 1; kk2 >= 0; --kk2) {  // uniform walk
        acc += hist[cb + kk2];      // acc = cum(cb+kk2)
        if (acc >= NDET) { B = cb + kk2; break; }
      }
    }
    if (lane == 0) s_bin = (u32)B;
  }
  __syncthreads();
  u32 B = s_bin;

#pragma unroll
  for (int v = 0; v < VPT; ++v) {  // compact bins > B (provably < NDET entries)
    u32 s = sc[v];
    if (s > SLO && ((s - SLO) >> SSH) > B) {
      u32 j = (u32)tid + (u32)v * 256u;
      u32 p = atomicAdd(&s_cnt[0], 1u);
      if (p < FKCAP) { fk[p] = kb[j]; fs[p] = j; }
    }
  }
  __syncthreads();
  if (tid == 0) s_cnt[1] = s_cnt[0];
  __syncthreads();
#pragma unroll
  for (int v = 0; v < VPT; ++v) {  // bin==B ties; order fixed by rank sort
    u32 s = sc[v];
    if (s > SLO && ((s - SLO) >> SSH) == B) {
      u32 j = (u32)tid + (u32)v * 256u;
      u32 p = atomicAdd(&s_cnt[1], 1u);
      if (p < FKCAP) { fk[p] = kb[j]; fs[p] = j; }
    }
  }
  __syncthreads();
  u32 tot = s_cnt[1];
  if (tot > FKCAP) tot = FKCAP;
  if (tid >= 64) return;  // wave 0 finishes barrier-free

  for (int i = tid; i < NDET; i += 64) okey[i] = 0ull;
  for (int i = tid; i < (int)tot; i += 64) {  // rank sort (keys unique)
    u64 ki = fk[i];
    u32 rank = 0;
    for (int j = 0; j < (int)tot; ++j) rank += (fk[j] > ki) ? 1u : 0u;
    if (rank < NDET) { okey[rank] = ki; osrc[rank] = fs[i]; }
  }
  // boxes[3200] | scores[800] | labels[800] | keep[800]
  for (int i = tid; i < NDET; i += 64) {
    u64 key = okey[i];
    float b0 = 0.f, b1 = 0.f, b2 = 0.f, b3 = 0.f, sc2 = 0.f, lb = 0.f, kp = 0.f;
    if (key) {
      float4 bx = sbox[(size_t)b * SURVCAP + osrc[i]];
      b0 = bx.x; b1 = bx.y; b2 = bx.z; b3 = bx.w;
      sc2 = __uint_as_float((u32)(key >> 22));
      u32 orig = 0x3FFFFFu - (u32)(key & 0x3FFFFFu);
      lb = (float)(orig % NCLS + 1u);
      kp = 1.0f;
    }
    float* ob = out + ((size_t)b * NDET + i) * 4;
    ob[0] = b0; ob[1] = b1; ob[2] = b2; ob[3] = b3;
    out[NB * NDET * 4 + b * NDET + i] = sc2;
    out[NB * NDET * 5 + b * NDET + i] = lb;
    out[NB * NDET * 6 + b * NDET + i] = kp;
  }
}

// ---------------------------------------------------------------- launch ----
extern "C" void kernel_launch(void* const* d_in, const int* in_sizes, int n_in,
                              void* d_out, int out_size, void* d_ws, size_t ws_size,
                              hipStream_t stream) {
  const float* logits = (const float*)d_in[0];
  const float* boxreg = (const float*)d_in[1];
  const float* props  = (const float*)d_in[2];
  const int* dh = (const int*)d_in[3];
  const int* dw = (const int*)d_in[4];
  float* out = (float*)d_out;

  char* ws = (char*)d_ws;
  u32* cnt_g = (u32*)ws;                                      // 8*64*90 u32 = 180 KiB
  char* p0 = ws + (((size_t)NB * CHUNKS * NCLS * 4 + 255) & ~(size_t)255);
  u64* bins_key = (u64*)p0;                                   // 8*64*90*63*8  = 23.2 MB
  char* p1 = p0 + (size_t)NB * CHUNKS * NCLS * CCAP * 8;
  float4* bins_box = (float4*)p1;                             // 8*64*90*63*16 = 46.4 MB
  char* p2 = p1 + (size_t)NB * CHUNKS * NCLS * CCAP * 16;
  u64* skey = (u64*)p2;                                       // 8*9216*8 = 590 KB
  float4* sbox = (float4*)(p2 + (size_t)NB * SURVCAP * 8);    // 8*9216*16 = 1.18 MB
  (void)ws_size;

  k_score<<<NB * CHUNKS, 512, 0, stream>>>(logits, boxreg, props, dh, dw,
                                           cnt_g, bins_key, bins_box);
  k_nms_class<<<NB * NCLS, 256, 0, stream>>>(cnt_g, bins_key, bins_box,
                                             skey, sbox, dh, dw);
  k_top<<<NB, 256, 0, stream>>>(skey, sbox, out);
}

// Round 4
// 156.898 us; speedup vs baseline: 1.0538x; 1.0538x over previous
//
#include <hip/hip_runtime.h>
#include <stdint.h>

typedef uint32_t u32;
typedef unsigned long long u64;

#define NB 8
#define NPER 4000
#define NC 91
#define NCLS 90
#define NDET 100
#define CHUNKS 64
#define RPB 63         // rows per k_score block; 64*63=4032 covers 4000 w/ guard
#define LBIN 16        // LDS staging per class per chunk (avg ~1.6 used)
#define CCAP 63        // per-(chunk,class) global bin cap == rows/chunk (EXACT)
#define BINCAP 512     // per-(image,class) NMS pool clamp (avg ~103)
#define SURVCAP 9216   // fixed survivor slots: 90 classes x 100 + pad
#define NSFIX (NCLS * NDET)  // 9000 real slots
#define FKCAP 1024     // k_top compacted pool (100 + bin-B ties)
#define VPT 36         // k_top values/thread = SURVCAP/256
#define NBIN 1152      // histogram bins over score bits; 1127 used (18/lane)
#define SLO 0x3D4CCCCEu  // bits(0.05); all survivor scores strictly above
#define SSH 15         // bin = (bits - SLO) >> SSH; max idx 0x2333333>>15 = 1126

// ---------------------------------------------------------------- decode ----
// bit-identical to reference op order (verified absmax 0.0 in R1-R16)
__device__ __forceinline__ float4 decode_clip(float4 rel, float w, float h,
                                              float cx, float cy, float W, float H) {
  const float XCLIP = 4.135166556742356f;  // log(1000/16)
  float dx = rel.x / 10.0f;
  float dy = rel.y / 10.0f;
  float dw = fminf(rel.z / 5.0f, XCLIP);
  float dh = fminf(rel.w / 5.0f, XCLIP);
  float qcx = dx * w + cx;
  float qcy = dy * h + cy;
  float qw = expf(dw) * w;
  float qh = expf(dh) * h;
  float x1 = qcx - 0.5f * qw, y1 = qcy - 0.5f * qh;
  float x2 = qcx + 0.5f * qw, y2 = qcy + 0.5f * qh;
  x1 = fminf(fmaxf(x1, 0.0f), W);
  x2 = fminf(fmaxf(x2, 0.0f), W);
  y1 = fminf(fmaxf(y1, 0.0f), H);
  y2 = fminf(fmaxf(y2, 0.0f), H);
  return make_float4(x1, y1, x2, y2);
}

__device__ __forceinline__ u64 rdlane64(u64 v, int sl) {
  u32 lo = (u32)__builtin_amdgcn_readlane((int)(u32)v, sl);
  u32 hi = (u32)__builtin_amdgcn_readlane((int)(u32)(v >> 32), sl);
  return ((u64)hi << 32) | (u64)lo;
}

// ---------------------------------------------------------------- k_score ---
__device__ __forceinline__ void emit_row(int r, int rl, int lane, float sA, float sB,
    float W, float H, const float4* __restrict__ props4, const float4* __restrict__ breg4,
    u32* s_cnt, u64 (*s_key)[LBIN], float4 (*s_box)[LBIN],
    size_t chbase, u64* __restrict__ bins_key, float4* __restrict__ bins_box) {
  bool eA_ok = (lane >= 1) && (sA > 0.05f);
  bool eB_ok = (lane < NC - 64) && (sB > 0.05f);
  if (!(eA_ok || eB_ok)) return;
  float4 p = props4[r];
  float w = p.z - p.x, h = p.w - p.y;
  float cx = p.x + 0.5f * w, cy = p.y + 0.5f * h;
  if (eA_ok) {
    float4 raw = decode_clip(breg4[(size_t)r * NC + lane], w, h, cx, cy, W, H);
    if (((raw.z - raw.x) >= 0.01f) && ((raw.w - raw.y) >= 0.01f)) {
      int ci = lane - 1;
      u32 orig = (u32)(rl * NCLS + ci);
      u64 key = ((u64)__float_as_uint(sA) << 22) | (u64)(0x3FFFFFu - orig);
      u32 lp = atomicAdd(&s_cnt[ci], 1u);  // LDS only
      if (lp < LBIN) { s_key[ci][lp] = key; s_box[ci][lp] = raw; }
      else if (lp < CCAP) {  // block-private global slot, no atomic
        size_t o = (chbase + ci) * CCAP + lp;
        bins_key[o] = key; bins_box[o] = raw;
      }
    }
  }
  if (eB_ok) {
    float4 raw = decode_clip(breg4[(size_t)r * NC + 64 + lane], w, h, cx, cy, W, H);
    if (((raw.z - raw.x) >= 0.01f) && ((raw.w - raw.y) >= 0.01f)) {
      int ci = 63 + lane;
      u32 orig = (u32)(rl * NCLS + ci);
      u64 key = ((u64)__float_as_uint(sB) << 22) | (u64)(0x3FFFFFu - orig);
      u32 lp = atomicAdd(&s_cnt[ci], 1u);
      if (lp < LBIN) { s_key[ci][lp] = key; s_box[ci][lp] = raw; }
      else if (lp < CCAP) {
        size_t o = (chbase + ci) * CCAP + lp;
        bins_key[o] = key; bins_box[o] = raw;
      }
    }
  }
}

// Front-end: softmax + decode + filter. R17: reverted to the 1024-thread R15
// configuration verbatim (the R16 512-thread variant halved resident waves
// and regressed ~4-6us -- k_score is latency-hiding-bound, not
// occupancy-quantum-bound). TWO rows per wave iteration with interleaved
// (independent) shfl-reduce chains; per-row op order bit-identical.
__global__ __launch_bounds__(1024) void k_score(const float* __restrict__ logits,
    const float* __restrict__ boxreg, const float* __restrict__ props,
    const int* __restrict__ dh, const int* __restrict__ dw,
    u32* cnt_g, u64* bins_key, float4* bins_box) {
  __shared__ u64 s_key[NCLS][LBIN];
  __shared__ float4 s_box[NCLS][LBIN];
  __shared__ u32 s_cnt[NCLS];
  int tid = threadIdx.x;
  int b = blockIdx.x / CHUNKS;
  int chunk = blockIdx.x % CHUNKS;
  int wave = tid >> 6, lane = tid & 63;
  if (tid < NCLS) s_cnt[tid] = 0u;
  __syncthreads();

  float H = (float)dh[0], W = (float)dw[0];
  const float4* props4 = (const float4*)props;
  const float4* breg4 = (const float4*)boxreg;
  size_t chbase = ((size_t)(b * CHUNKS + chunk)) * NCLS;  // *CCAP for bins

  for (int rloc = wave; rloc < RPB; rloc += 32) {
    int rloc1 = rloc + 16;
    int rl0 = chunk * RPB + rloc;
    int rl1 = chunk * RPB + rloc1;
    bool v0 = (rl0 < NPER);
    bool v1 = (rloc1 < RPB) && (rl1 < NPER);
    int r0 = b * NPER + (v0 ? rl0 : 0);
    int r1 = b * NPER + (v1 ? rl1 : 0);
    const float* l0 = logits + (size_t)r0 * NC;
    const float* l1 = logits + (size_t)r1 * NC;
    float xA0 = l0[lane];
    float xA1 = l1[lane];
    float xB0 = (lane < NC - 64) ? l0[64 + lane] : -3.0e38f;
    float xB1 = (lane < NC - 64) ? l1[64 + lane] : -3.0e38f;
    float mx0 = fmaxf(xA0, xB0);
    float mx1 = fmaxf(xA1, xB1);
    for (int o = 32; o; o >>= 1) {
      mx0 = fmaxf(mx0, __shfl_xor(mx0, o));
      mx1 = fmaxf(mx1, __shfl_xor(mx1, o));
    }
    float eA0 = expf(xA0 - mx0);
    float eA1 = expf(xA1 - mx1);
    float eB0 = (lane < NC - 64) ? expf(xB0 - mx0) : 0.0f;
    float eB1 = (lane < NC - 64) ? expf(xB1 - mx1) : 0.0f;
    float sm0 = eA0 + eB0;
    float sm1 = eA1 + eB1;
    for (int o = 32; o; o >>= 1) {
      sm0 += __shfl_xor(sm0, o);
      sm1 += __shfl_xor(sm1, o);
    }
    if (v0) emit_row(r0, rl0, lane, eA0 / sm0, eB0 / sm0, W, H, props4, breg4,
                     s_cnt, s_key, s_box, chbase, bins_key, bins_box);
    if (v1) emit_row(r1, rl1, lane, eA1 / sm1, eB1 / sm1, W, H, props4, breg4,
                     s_cnt, s_key, s_box, chbase, bins_key, bins_box);
  }
  __syncthreads();
  if (tid < NCLS) cnt_g[chbase + tid] = s_cnt[tid];  // plain store
  for (int idx = tid; idx < NCLS * LBIN; idx += 1024) {  // cooperative LDS flush
    int ci = idx / LBIN, j = idx % LBIN;
    if ((u32)j < s_cnt[ci]) {
      size_t o = (chbase + ci) * CCAP + (u32)j;
      bins_key[o] = s_key[ci][j];
      bins_box[o] = s_box[ci][j];
    }
  }
}

// Per-(image,class) greedy NMS. R17: WORD-GREEDY -- per 64-candidate batch,
// every lane precomputes its 64-bit suppression word (bit m = "candidate m
// suppresses me", 64 parallel IoUs, LDS broadcast reads) BEFORE the walk.
// The greedy walk is then pure scalar: j0=ctz(mask); sel|=bit;
// row=2xreadlane; mask&=~row (~30 cyc/round vs ~700 measured for the old
// per-round {5xreadlane+IoU+ballot} chain, which R16's counters showed as
// the bottleneck: 40us, VALUBusy 25%, Occ 11%). Selection within a batch is
// ascending-index, so survivors are recorded AFTER the walk at
// rank = S + popc(sel below lane) -- order identical to sequential greedy.
// Suppression predicate bit-identical: same op order, A-side rebuilt as
// boxs[m]+loff (exact bits of lane m's own Bb); self-bit (IoU=1) removes
// the selected candidate; cross-batch suppression via s_sb loop unchanged.
__global__ __launch_bounds__(256) void k_nms_class(const u32* __restrict__ cnt_g,
    const u64* __restrict__ bins_key, const float4* __restrict__ bins_box,
    u64* skey, float4* sbox, const int* __restrict__ dh, const int* __restrict__ dw) {
  __shared__ u64 k[BINCAP];       // unsorted keys
  __shared__ float4 boxu[BINCAP]; // unsorted boxes
  __shared__ u64 ks[BINCAP];      // rank-sorted keys (desc)
  __shared__ float4 boxs[BINCAP]; // rank-sorted boxes
  __shared__ float4 s_sb[NDET];   // survivor offset boxes (IoU space)
  __shared__ float s_sa[NDET];
  __shared__ u64 s_sk[NDET];
  __shared__ u32 s_sid[NDET];
  __shared__ u32 s_off[64];
  __shared__ u32 s_c[64];
  __shared__ u32 s_n;

  int b = blockIdx.x / NCLS;
  int ci = blockIdx.x % NCLS;
  int tid = threadIdx.x;
  u64* outk = skey + (size_t)b * SURVCAP + (size_t)ci * NDET;
  float4* outb = sbox + (size_t)b * SURVCAP + (size_t)ci * NDET;

  if (tid < 64) {  // lane == chunk: counts + wave prefix scan
    u32 c = cnt_g[((size_t)(b * CHUNKS + tid)) * NCLS + ci];
    if (c > CCAP) c = CCAP;
    s_c[tid] = c;
    u32 inc = c;
    for (int o = 1; o < 64; o <<= 1) {
      u32 v = __shfl_up(inc, o);
      if (tid >= o) inc += v;
    }
    s_off[tid] = inc - c;
    if (tid == 63) s_n = (inc > BINCAP) ? BINCAP : inc;
  }
  __syncthreads();
  int n = (int)s_n;
  if (n <= 0) {
    for (int i = tid; i < NDET; i += 256) outk[i] = 0ull;
    return;
  }
  {  // cooperative gather: 4 threads per chunk
    int chunk = tid & 63, start = tid >> 6;
    u32 cc = s_c[chunk], of = s_off[chunk];
    size_t src = (((size_t)(b * CHUNKS + chunk)) * NCLS + ci) * CCAP;
    for (u32 i = (u32)start; i < cc; i += 4) {
      u32 d = of + i;
      if (d < (u32)BINCAP) { k[d] = bins_key[src + i]; boxu[d] = bins_box[src + i]; }
    }
  }
  __syncthreads();
  for (int i = tid; i < n; i += 256) {  // rank sort: broadcast reads, no barriers
    u64 ki = k[i];
    u32 rank = 0;
    int j = 0;
    for (; j + 4 <= n; j += 4) {
      rank += (k[j] > ki) ? 1u : 0u;
      rank += (k[j + 1] > ki) ? 1u : 0u;
      rank += (k[j + 2] > ki) ? 1u : 0u;
      rank += (k[j + 3] > ki) ? 1u : 0u;
    }
    for (; j < n; ++j) rank += (k[j] > ki) ? 1u : 0u;
    ks[rank] = ki;
    boxs[rank] = boxu[i];
  }
  __syncthreads();
  if (tid >= 64) return;  // wave 0 continues barrier-free

  float H = (float)dh[0], W = (float)dw[0];
  float loff = (fmaxf(H, W) + 1.0f) * (float)(ci + 1);
  int lane = tid;
  int S = 0;
  for (int base = 0; base < n && S < NDET; base += 64) {
    int i = base + lane;
    bool have = (i < n);
    u64 mykey = 0ull;
    float4 Bb = make_float4(0.f, 0.f, 0.f, 0.f);
    float aB = 0.f;
    if (have) {
      mykey = ks[i];
      float4 raw = boxs[i];
      Bb = make_float4(raw.x + loff, raw.y + loff, raw.z + loff, raw.w + loff);
      aB = (Bb.z - Bb.x) * (Bb.w - Bb.y);
    }
    // in-batch suppression word: bit m = "candidate m would suppress me".
    // A-side = boxs[base+m]+loff: exact bits of lane m's own Bb; aA likewise.
    // Self-bit m==lane: IoU=1 > 0.5 -> set (removes selected from mask).
    u64 myword = 0ull;
    int lim = n - base; if (lim > 64) lim = 64;
#pragma unroll 4
    for (int m = 0; m < lim; ++m) {
      float4 As = boxs[base + m];
      float ax = As.x + loff, ay = As.y + loff;
      float az = As.z + loff, aw = As.w + loff;
      float aA = (az - ax) * (aw - ay);
      float ix1 = fmaxf(ax, Bb.x), iy1 = fmaxf(ay, Bb.y);
      float ix2 = fminf(az, Bb.z), iy2 = fminf(aw, Bb.w);
      float inter = fmaxf(ix2 - ix1, 0.0f) * fmaxf(iy2 - iy1, 0.0f);
      float iou = inter / fmaxf(aA + aB - inter, 1e-9f);
      if (iou > 0.5f) myword |= (1ull << m);
    }
    bool alive = have;
    for (int s = 0; s < S; ++s) {  // cross-batch suppression, unchanged
      float4 A = s_sb[s];
      float aA = s_sa[s];
      float ix1 = fmaxf(A.x, Bb.x), iy1 = fmaxf(A.y, Bb.y);
      float ix2 = fminf(A.z, Bb.z), iy2 = fminf(A.w, Bb.w);
      float inter = fmaxf(ix2 - ix1, 0.0f) * fmaxf(iy2 - iy1, 0.0f);
      float iou = inter / fmaxf(aA + aB - inter, 1e-9f);
      if (alive && iou > 0.5f) alive = false;
    }
    // scalar mask walk: selection order == ascending index == sequential
    u64 mask = __ballot(alive);
    u64 sel = 0ull;
    while (mask != 0ull && S + (int)__popcll(sel) < NDET) {
      int j0 = __builtin_amdgcn_readfirstlane(__builtin_ctzll(mask));
      sel |= (1ull << j0);
      u64 row = rdlane64(myword, j0);
      mask &= ~row;   // includes self-bit -> j0 leaves
    }
    // record survivors post-walk at their sequential ranks
    if ((sel >> lane) & 1ull) {
      int rank = S + (int)__popcll(sel & ((1ull << lane) - 1ull));
      s_sb[rank] = Bb; s_sa[rank] = aB; s_sk[rank] = mykey; s_sid[rank] = (u32)i;
    }
    S += (int)__popcll(sel);
  }
  for (int i2 = lane; i2 < NDET; i2 += 64) {  // fixed slots, zero-padded
    if (i2 < S) {
      outk[i2] = s_sk[i2];
      outb[i2] = boxs[s_sid[i2]];
    } else {
      outk[i2] = 0ull;
    }
  }
}

// Per-image exact top-NDET over the fixed 9000 survivor slots (key==0 =
// empty, never selectable). R15 structure: ONE LDS histogram pass over the
// score bits + in-wave suffix scan locates threshold bin B (bin index is
// monotone in the score field; cum(B) >= NDET contains the exact top-100;
// count(bins > B) < NDET by maximality). Two-pass compact (bins>B then
// bin==B ties, FKCAP clamp) + rank sort -> bit-identical outputs.
__global__ __launch_bounds__(256) void k_top(const u64* __restrict__ skey,
    const float4* __restrict__ sbox, float* out) {
  __shared__ u32 hist[NBIN];
  __shared__ u64 fk[FKCAP];
  __shared__ u32 fs[FKCAP];
  __shared__ u64 okey[NDET];
  __shared__ u32 osrc[NDET];
  __shared__ u32 s_cnt[2];
  __shared__ u32 s_bin;

  int b = blockIdx.x;
  int tid = threadIdx.x;
  const u64* kb = skey + (size_t)b * SURVCAP;

  u32 sc[VPT];
#pragma unroll
  for (int v = 0; v < VPT; ++v) {
    u32 j = (u32)tid + (u32)v * 256u;
    sc[v] = (j < NSFIX) ? (u32)(kb[j] >> 22) : 0u;  // key==0 slots -> score 0
  }
  for (int i = tid; i < NBIN; i += 256) hist[i] = 0u;
  if (tid == 0) { s_cnt[0] = 0; s_cnt[1] = 0; }
  __syncthreads();

#pragma unroll
  for (int v = 0; v < VPT; ++v) {
    u32 s = sc[v];
    if (s > SLO) atomicAdd(&hist[(s - SLO) >> SSH], 1u);
  }
  __syncthreads();

  // wave 0: largest bin B with cum(B) = count(bins >= B) >= NDET; B=0 if none
  if (tid < 64) {
    int lane = tid;
    int base = lane * (NBIN / 64);  // 18 contiguous bins per lane
    u32 csum = 0;
#pragma unroll
    for (int kk2 = 0; kk2 < NBIN / 64; ++kk2) csum += hist[base + kk2];
    u32 suf = csum;                 // inclusive suffix scan across lanes
    for (int o = 1; o < 64; o <<= 1) {
      u32 v = __shfl_down(suf, o);
      if (lane + o < 64) suf += v;
    }
    u64 m = __ballot(suf >= NDET);  // prefix mask (suf non-increasing in lane)
    int B = 0;
    if (m) {
      int c = 63 - __builtin_clzll(m);              // largest chunk with suf>=NDET
      u32 rest = (c < 63) ? (u32)__shfl((int)suf, c + 1) : 0u;  // uniform
      u32 acc = rest;
      int cb = c * (NBIN / 64);
      for (int kk2 = (NBIN / 64) - 1; kk2 >= 0; --kk2) {  // uniform walk
        acc += hist[cb + kk2];      // acc = cum(cb+kk2)
        if (acc >= NDET) { B = cb + kk2; break; }
      }
    }
    if (lane == 0) s_bin = (u32)B;
  }
  __syncthreads();
  u32 B = s_bin;

#pragma unroll
  for (int v = 0; v < VPT; ++v) {  // compact bins > B (provably < NDET entries)
    u32 s = sc[v];
    if (s > SLO && ((s - SLO) >> SSH) > B) {
      u32 j = (u32)tid + (u32)v * 256u;
      u32 p = atomicAdd(&s_cnt[0], 1u);
      if (p < FKCAP) { fk[p] = kb[j]; fs[p] = j; }
    }
  }
  __syncthreads();
  if (tid == 0) s_cnt[1] = s_cnt[0];
  __syncthreads();
#pragma unroll
  for (int v = 0; v < VPT; ++v) {  // bin==B ties; order fixed by rank sort
    u32 s = sc[v];
    if (s > SLO && ((s - SLO) >> SSH) == B) {
      u32 j = (u32)tid + (u32)v * 256u;
      u32 p = atomicAdd(&s_cnt[1], 1u);
      if (p < FKCAP) { fk[p] = kb[j]; fs[p] = j; }
    }
  }
  __syncthreads();
  u32 tot = s_cnt[1];
  if (tot > FKCAP) tot = FKCAP;
  if (tid >= 64) return;  // wave 0 finishes barrier-free

  for (int i = tid; i < NDET; i += 64) okey[i] = 0ull;
  for (int i = tid; i < (int)tot; i += 64) {  // rank sort (keys unique)
    u64 ki = fk[i];
    u32 rank = 0;
    for (int j = 0; j < (int)tot; ++j) rank += (fk[j] > ki) ? 1u : 0u;
    if (rank < NDET) { okey[rank] = ki; osrc[rank] = fs[i]; }
  }
  // boxes[3200] | scores[800] | labels[800] | keep[800]
  for (int i = tid; i < NDET; i += 64) {
    u64 key = okey[i];
    float b0 = 0.f, b1 = 0.f, b2 = 0.f, b3 = 0.f, sc2 = 0.f, lb = 0.f, kp = 0.f;
    if (key) {
      float4 bx = sbox[(size_t)b * SURVCAP + osrc[i]];
      b0 = bx.x; b1 = bx.y; b2 = bx.z; b3 = bx.w;
      sc2 = __uint_as_float((u32)(key >> 22));
      u32 orig = 0x3FFFFFu - (u32)(key & 0x3FFFFFu);
      lb = (float)(orig % NCLS + 1u);
      kp = 1.0f;
    }
    float* ob = out + ((size_t)b * NDET + i) * 4;
    ob[0] = b0; ob[1] = b1; ob[2] = b2; ob[3] = b3;
    out[NB * NDET * 4 + b * NDET + i] = sc2;
    out[NB * NDET * 5 + b * NDET + i] = lb;
    out[NB * NDET * 6 + b * NDET + i] = kp;
  }
}

// ---------------------------------------------------------------- launch ----
extern "C" void kernel_launch(void* const* d_in, const int* in_sizes, int n_in,
                              void* d_out, int out_size, void* d_ws, size_t ws_size,
                              hipStream_t stream) {
  const float* logits = (const float*)d_in[0];
  const float* boxreg = (const float*)d_in[1];
  const float* props  = (const float*)d_in[2];
  const int* dh = (const int*)d_in[3];
  const int* dw = (const int*)d_in[4];
  float* out = (float*)d_out;

  char* ws = (char*)d_ws;
  u32* cnt_g = (u32*)ws;                                      // 8*64*90 u32 = 180 KiB
  char* p0 = ws + (((size_t)NB * CHUNKS * NCLS * 4 + 255) & ~(size_t)255);
  u64* bins_key = (u64*)p0;                                   // 8*64*90*63*8  = 23.2 MB
  char* p1 = p0 + (size_t)NB * CHUNKS * NCLS * CCAP * 8;
  float4* bins_box = (float4*)p1;                             // 8*64*90*63*16 = 46.4 MB
  char* p2 = p1 + (size_t)NB * CHUNKS * NCLS * CCAP * 16;
  u64* skey = (u64*)p2;                                       // 8*9216*8 = 590 KB
  float4* sbox = (float4*)(p2 + (size_t)NB * SURVCAP * 8);    // 8*9216*16 = 1.18 MB
  (void)ws_size;

  k_score<<<NB * CHUNKS, 1024, 0, stream>>>(logits, boxreg, props, dh, dw,
                                            cnt_g, bins_key, bins_box);
  k_nms_class<<<NB * NCLS, 256, 0, stream>>>(cnt_g, bins_key, bins_box,
                                             skey, sbox, dh, dw);
  k_top<<<NB, 256, 0, stream>>>(skey, sbox, out);
}